// Round 2
// baseline (1306.747 us; speedup 1.0000x reference)
//
#include <hip/hip_runtime.h>
#include <hip/hip_bf16.h>

// Problem constants (match reference)
#define D_MODEL 2048
#define SEQ_T   2048
#define NQH     16
#define NKVH    4
#define HD      128
#define WIN     256
#define BATCH   2
#define ROWS    (BATCH * SEQ_T)   // 4096

typedef __attribute__((ext_vector_type(8))) short bf8_t;   // 8 bf16 in 4 VGPRs
typedef __attribute__((ext_vector_type(4))) float f4_t;    // MFMA acc

__device__ __forceinline__ float bf2f(unsigned short u) {
    union { unsigned int i; float f; } v; v.i = ((unsigned int)u) << 16; return v.f;
}
__device__ __forceinline__ unsigned short f2bf(float f) {
    union { float f; unsigned int i; } v; v.f = f;
    unsigned int x = v.i;
    unsigned int lsb = (x >> 16) & 1u;
    x += 0x7fffu + lsb;           // round-to-nearest-even (finite values only)
    return (unsigned short)(x >> 16);
}

// Dtype sniff: p points at Wq (gaussian, sigma=1/sqrt(2048)).
// If buffer is bf16: even-index u16 are real bf16 values -> exponent ~[117,124].
// If buffer is fp32: even-index u16 are low mantissa bits -> exponent uniform.
__device__ int sniff_is_f32(const unsigned short* p) {
    int sane = 0;
    for (int i = 0; i < 64; ++i) {
        unsigned short u = p[2 * i];
        int e = (u >> 7) & 0xFF;
        sane += (e >= 100 && e <= 140) ? 1 : 0;
    }
    return sane < 32;   // bf16 buffer => ~64 sane; fp32 => ~10
}

// ---------------------------------------------------------------------------
// GEMM: C[M,N] = A[M,K] * B[K,N], fp32 accumulate via bf16 MFMA.
// Dual-dtype: A (if a_dyn) and B follow the sniffed input dtype; C is written
// as bf16 unless (c_dyn && inputs are fp32).
// Block: 256 threads = 4 waves (2x2), tile 64x64, BK=32.
// Fragment layouts (HW-verified gfx950 mapping):
//   A[m=lane&15][k=quad*8+j]; B[k=quad*8+j][n=lane&15]; D col=lane&15,row=quad*4+reg
// ---------------------------------------------------------------------------
__global__ __launch_bounds__(256)
void gemm_dual(const void* __restrict__ A,
               const void* __restrict__ B,
               void* __restrict__ C,
               int M, int N, int Kd,
               const unsigned short* __restrict__ sniffp,
               int a_dyn, int c_dyn) {
    __shared__ unsigned short As[64][32];   // As[m][k]
    __shared__ unsigned short Bs[64][32];   // Bs[n][k]  (B transposed)
    __shared__ int s_f32;

    const int t = threadIdx.x;
    if (t == 0) s_f32 = sniff_is_f32(sniffp);

    const int m0   = blockIdx.y * 64;
    const int n0   = blockIdx.x * 64;
    const int w    = t >> 6;
    const int lane = t & 63;
    const int wm   = w >> 1;        // 0..1
    const int wn   = w & 1;         // 0..1
    const int quad = lane >> 4;     // 0..3
    const int lr   = lane & 15;     // 0..15

    f4_t acc[2][2];
    #pragma unroll
    for (int i = 0; i < 2; ++i)
        #pragma unroll
        for (int j = 0; j < 2; ++j)
            acc[i][j] = (f4_t){0.f, 0.f, 0.f, 0.f};

    const int ar = t >> 2;          // 0..63  A row
    const int ac = (t & 3) * 8;     // 0,8,16,24
    const int bk = t >> 3;          // 0..31  B row (k)
    const int bn = (t & 7) * 8;     // 0..56  B col

    __syncthreads();
    const bool in_f32 = (s_f32 != 0);
    const bool a_f32  = in_f32 && (a_dyn != 0);
    const bool c_f32  = in_f32 && (c_dyn != 0);

    for (int k0 = 0; k0 < Kd; k0 += 32) {
        __syncthreads();
        // ---- stage A tile ----
        if (a_f32) {
            const float* Af = (const float*)A;
            const float4* pa = (const float4*)(Af + (size_t)(m0 + ar) * Kd + k0 + ac);
            float4 a0 = pa[0], a1 = pa[1];
            unsigned short* d = &As[ar][ac];
            d[0] = f2bf(a0.x); d[1] = f2bf(a0.y); d[2] = f2bf(a0.z); d[3] = f2bf(a0.w);
            d[4] = f2bf(a1.x); d[5] = f2bf(a1.y); d[6] = f2bf(a1.z); d[7] = f2bf(a1.w);
        } else {
            const unsigned short* Au = (const unsigned short*)A;
            uint4 av = *(const uint4*)(Au + (size_t)(m0 + ar) * Kd + k0 + ac);
            *(uint4*)(&As[ar][ac]) = av;
        }
        // ---- stage B tile (transposed) ----
        if (in_f32) {
            const float* Bf = (const float*)B;
            const float4* pb = (const float4*)(Bf + (size_t)(k0 + bk) * N + n0 + bn);
            float4 b0 = pb[0], b1 = pb[1];
            Bs[bn + 0][bk] = f2bf(b0.x); Bs[bn + 1][bk] = f2bf(b0.y);
            Bs[bn + 2][bk] = f2bf(b0.z); Bs[bn + 3][bk] = f2bf(b0.w);
            Bs[bn + 4][bk] = f2bf(b1.x); Bs[bn + 5][bk] = f2bf(b1.y);
            Bs[bn + 6][bk] = f2bf(b1.z); Bs[bn + 7][bk] = f2bf(b1.w);
        } else {
            const unsigned short* Bu = (const unsigned short*)B;
            uint4 bv = *(const uint4*)(Bu + (size_t)(k0 + bk) * N + n0 + bn);
            union { uint4 v; unsigned short s[8]; } bu; bu.v = bv;
            #pragma unroll
            for (int j = 0; j < 8; ++j) Bs[bn + j][bk] = bu.s[j];
        }
        __syncthreads();

        bf8_t va0 = *reinterpret_cast<const bf8_t*>(&As[wm * 32 + 0  + lr][quad * 8]);
        bf8_t va1 = *reinterpret_cast<const bf8_t*>(&As[wm * 32 + 16 + lr][quad * 8]);
        bf8_t vb0 = *reinterpret_cast<const bf8_t*>(&Bs[wn * 32 + 0  + lr][quad * 8]);
        bf8_t vb1 = *reinterpret_cast<const bf8_t*>(&Bs[wn * 32 + 16 + lr][quad * 8]);

        acc[0][0] = __builtin_amdgcn_mfma_f32_16x16x32_bf16(va0, vb0, acc[0][0], 0, 0, 0);
        acc[0][1] = __builtin_amdgcn_mfma_f32_16x16x32_bf16(va0, vb1, acc[0][1], 0, 0, 0);
        acc[1][0] = __builtin_amdgcn_mfma_f32_16x16x32_bf16(va1, vb0, acc[1][0], 0, 0, 0);
        acc[1][1] = __builtin_amdgcn_mfma_f32_16x16x32_bf16(va1, vb1, acc[1][1], 0, 0, 0);
    }

    #pragma unroll
    for (int mi = 0; mi < 2; ++mi)
        #pragma unroll
        for (int ni = 0; ni < 2; ++ni)
            #pragma unroll
            for (int r = 0; r < 4; ++r) {
                int row = m0 + wm * 32 + mi * 16 + quad * 4 + r;
                int col = n0 + wn * 32 + ni * 16 + lr;
                if (c_f32) ((float*)C)[(size_t)row * N + col] = acc[mi][ni][r];
                else ((unsigned short*)C)[(size_t)row * N + col] = f2bf(acc[mi][ni][r]);
            }
}

// ---------------------------------------------------------------------------
// RoPE in-place on [ROWS, nheads*128] bf16. One block = (row, head), 64 threads.
// ---------------------------------------------------------------------------
__global__ __launch_bounds__(64)
void rope_kernel(unsigned short* __restrict__ X, int nheads) {
    const int idx = blockIdx.x;
    const int h   = idx % nheads;
    const int row = idx / nheads;
    const int tpos = row % SEQ_T;
    const int i   = threadIdx.x;   // 0..63

    size_t base = (size_t)row * (nheads * HD) + h * HD;
    float inv = exp2f(-(float)i * (13.287712379549449f / 64.0f));  // 10000^(-i/64)
    float a = (float)tpos * inv;
    float s, c;
    sincosf(a, &s, &c);
    float x0 = bf2f(X[base + i]);
    float x1 = bf2f(X[base + i + 64]);
    X[base + i]      = f2bf(x0 * c - x1 * s);
    X[base + i + 64] = f2bf(x1 * c + x0 * s);
}

// ---------------------------------------------------------------------------
// Sliding-window attention, flash-style online softmax.
// Writes O IN PLACE over Q (each block touches only its own Q tile, which it
// loads to LDS before any write).
// ---------------------------------------------------------------------------
__global__ __launch_bounds__(256)
void attn_kernel(unsigned short* __restrict__ Q,   // in: roped Q, out: attn O
                 const unsigned short* __restrict__ K,
                 const unsigned short* __restrict__ V) {
    __shared__ unsigned short Qs[32][HD];
    __shared__ unsigned short Ks[32][HD];
    __shared__ unsigned short Vs[32][HD];
    __shared__ float Ps[32][32];
    __shared__ float m_s[32], l_s[32], al_s[32];

    const int t  = threadIdx.x;
    const int b  = blockIdx.z;
    const int h  = blockIdx.y;
    const int q0 = blockIdx.x * 32;
    const int kvh = h >> 2;                 // N_REP = 4

    const int r8  = t >> 3;                 // 0..31
    const int c16 = (t & 7) * 16;           // 0..112
    const float scale = 0.08838834764831845f;  // 1/sqrt(128)

    {
        const uint4* src = reinterpret_cast<const uint4*>(
            Q + (size_t)(b * SEQ_T + q0 + r8) * D_MODEL + h * HD + c16);
        *reinterpret_cast<uint4*>(&Qs[r8][c16])     = src[0];
        *reinterpret_cast<uint4*>(&Qs[r8][c16 + 8]) = src[1];
    }
    if (t < 32) { m_s[t] = -3.0e38f; l_s[t] = 0.f; }

    float O[16];
    #pragma unroll
    for (int i = 0; i < 16; ++i) O[i] = 0.f;

    int kb_start = q0 - WIN;
    if (kb_start < 0) kb_start = 0;

    for (int kb = kb_start; kb <= q0; kb += 32) {
        __syncthreads();   // previous PV done before overwriting K/V
        {
            const uint4* sk = reinterpret_cast<const uint4*>(
                K + (size_t)(b * SEQ_T + kb + r8) * (NKVH * HD) + kvh * HD + c16);
            *reinterpret_cast<uint4*>(&Ks[r8][c16])     = sk[0];
            *reinterpret_cast<uint4*>(&Ks[r8][c16 + 8]) = sk[1];
            const uint4* sv = reinterpret_cast<const uint4*>(
                V + (size_t)(b * SEQ_T + kb + r8) * (NKVH * HD) + kvh * HD + c16);
            *reinterpret_cast<uint4*>(&Vs[r8][c16])     = sv[0];
            *reinterpret_cast<uint4*>(&Vs[r8][c16 + 8]) = sv[1];
        }
        __syncthreads();

        // Scores: thread -> row r8, cols (t&7)+{0,8,16,24}
        {
            const int c0 = t & 7;
            float s0 = 0.f, s1 = 0.f, s2 = 0.f, s3 = 0.f;
            #pragma unroll 4
            for (int d = 0; d < HD; ++d) {
                float qd = bf2f(Qs[r8][d]);
                s0 += qd * bf2f(Ks[c0][d]);
                s1 += qd * bf2f(Ks[c0 + 8][d]);
                s2 += qd * bf2f(Ks[c0 + 16][d]);
                s3 += qd * bf2f(Ks[c0 + 24][d]);
            }
            const int i_g = q0 + r8;
            float sv[4] = {s0, s1, s2, s3};
            #pragma unroll
            for (int jj = 0; jj < 4; ++jj) {
                int j_g = kb + c0 + jj * 8;
                bool ok = (j_g <= i_g) && (i_g - j_g < WIN);
                Ps[r8][c0 + jj * 8] = ok ? sv[jj] * scale : -3.0e38f;
            }
        }
        __syncthreads();

        // Online softmax row update (threads 0..31, one row each)
        if (t < 32) {
            float cmax = -3.0e38f;
            #pragma unroll 8
            for (int j = 0; j < 32; ++j) cmax = fmaxf(cmax, Ps[t][j]);
            float m_old = m_s[t];
            float m_new = fmaxf(m_old, cmax);
            float alpha = __expf(m_old - m_new);
            float rsum = 0.f;
            #pragma unroll 8
            for (int j = 0; j < 32; ++j) {
                float sj = Ps[t][j];
                float p = (sj <= -1.0e37f) ? 0.f : __expf(sj - m_new);
                Ps[t][j] = p;
                rsum += p;
            }
            l_s[t] = l_s[t] * alpha + rsum;
            m_s[t] = m_new;
            al_s[t] = alpha;
        }
        __syncthreads();

        // PV accumulate: thread owns (row r8, dims c16..c16+15)
        {
            float a = al_s[r8];
            #pragma unroll
            for (int i = 0; i < 16; ++i) O[i] *= a;
            #pragma unroll 4
            for (int j = 0; j < 32; ++j) {
                float p = Ps[r8][j];
                #pragma unroll
                for (int i = 0; i < 16; ++i)
                    O[i] += p * bf2f(Vs[j][c16 + i]);
            }
        }
    }

    // Epilogue: normalize and store in place over Q
    float inv = 1.0f / l_s[r8];
    unsigned short* dst = Q + (size_t)(b * SEQ_T + q0 + r8) * D_MODEL + h * HD + c16;
    #pragma unroll
    for (int i = 0; i < 16; ++i) dst[i] = f2bf(O[i] * inv);
}

// ---------------------------------------------------------------------------
extern "C" void kernel_launch(void* const* d_in, const int* in_sizes, int n_in,
                              void* d_out, int out_size, void* d_ws, size_t ws_size,
                              hipStream_t stream) {
    const void* x  = d_in[0];
    const void* Wq = d_in[1];
    const void* Wk = d_in[2];
    const void* Wv = d_in[3];
    const void* Wo = d_in[4];
    const unsigned short* sniffp = (const unsigned short*)d_in[1];

    // Workspace (bf16, 24 MB): Q[4096*2048] K[4096*512] V[4096*512]
    unsigned short* Qb = (unsigned short*)d_ws;
    unsigned short* Kb = Qb + (size_t)ROWS * D_MODEL;
    unsigned short* Vb = Kb + (size_t)ROWS * (NKVH * HD);

    dim3 blk(256);
    // Q = x @ Wq
    gemm_dual<<<dim3(D_MODEL / 64, ROWS / 64), blk, 0, stream>>>(
        x, Wq, Qb, ROWS, D_MODEL, D_MODEL, sniffp, 1, 0);
    // K = x @ Wk
    gemm_dual<<<dim3((NKVH * HD) / 64, ROWS / 64), blk, 0, stream>>>(
        x, Wk, Kb, ROWS, NKVH * HD, D_MODEL, sniffp, 1, 0);
    // V = x @ Wv
    gemm_dual<<<dim3((NKVH * HD) / 64, ROWS / 64), blk, 0, stream>>>(
        x, Wv, Vb, ROWS, NKVH * HD, D_MODEL, sniffp, 1, 0);
    // RoPE on Q and K
    rope_kernel<<<dim3(ROWS * NQH), dim3(64), 0, stream>>>(Qb, NQH);
    rope_kernel<<<dim3(ROWS * NKVH), dim3(64), 0, stream>>>(Kb, NKVH);
    // Attention: O overwrites Q in place
    attn_kernel<<<dim3(SEQ_T / 32, NQH, BATCH), dim3(256), 0, stream>>>(Qb, Kb, Vb);
    // out = O @ Wo   (output dtype follows sniffed input dtype)
    gemm_dual<<<dim3(D_MODEL / 64, ROWS / 64), blk, 0, stream>>>(
        Qb, Wo, d_out, ROWS, D_MODEL, D_MODEL, sniffp, 0, 1);
}

// Round 3
// 687.564 us; speedup vs baseline: 1.9005x; 1.9005x over previous
//
#include <hip/hip_runtime.h>
#include <hip/hip_bf16.h>

// Problem constants (match reference)
#define D_MODEL 2048
#define SEQ_T   2048
#define NQH     16
#define NKVH    4
#define HD      128
#define WIN     256
#define BATCH   2
#define ROWS    (BATCH * SEQ_T)   // 4096

typedef __attribute__((ext_vector_type(8))) short bf8_t;   // 8 bf16 in 4 VGPRs
typedef __attribute__((ext_vector_type(4))) float f4_t;    // MFMA acc

__device__ __forceinline__ float bf2f(unsigned short u) {
    union { unsigned int i; float f; } v; v.i = ((unsigned int)u) << 16; return v.f;
}
__device__ __forceinline__ unsigned short f2bf(float f) {
    union { float f; unsigned int i; } v; v.f = f;
    unsigned int x = v.i;
    unsigned int lsb = (x >> 16) & 1u;
    x += 0x7fffu + lsb;           // round-to-nearest-even (finite values only)
    return (unsigned short)(x >> 16);
}

// Dtype sniff (inputs are fp32 per round-2 result; keep sniff for robustness).
__device__ int sniff_is_f32(const unsigned short* p) {
    int sane = 0;
    for (int i = 0; i < 64; ++i) {
        unsigned short u = p[2 * i];
        int e = (u >> 7) & 0xFF;
        sane += (e >= 100 && e <= 140) ? 1 : 0;
    }
    return sane < 32;
}

// ---------------------------------------------------------------------------
// GEMM: C[M,N] = A[M,K] * B[K,N], fp32 accumulate via bf16 MFMA.
// c_trans: store C transposed (Ct[col][row], leading dim M) as bf16 —
// used for V so attention can read V key-major (B-fragment layout).
// ---------------------------------------------------------------------------
__global__ __launch_bounds__(256)
void gemm_dual(const void* __restrict__ A,
               const void* __restrict__ B,
               void* __restrict__ C,
               int M, int N, int Kd,
               const unsigned short* __restrict__ sniffp,
               int a_dyn, int c_dyn, int c_trans) {
    __shared__ unsigned short As[64][32];
    __shared__ unsigned short Bs[64][32];
    __shared__ int s_f32;

    const int t = threadIdx.x;
    if (t == 0) s_f32 = sniff_is_f32(sniffp);

    const int m0   = blockIdx.y * 64;
    const int n0   = blockIdx.x * 64;
    const int w    = t >> 6;
    const int lane = t & 63;
    const int wm   = w >> 1;
    const int wn   = w & 1;
    const int quad = lane >> 4;
    const int lr   = lane & 15;

    f4_t acc[2][2];
    #pragma unroll
    for (int i = 0; i < 2; ++i)
        #pragma unroll
        for (int j = 0; j < 2; ++j)
            acc[i][j] = (f4_t){0.f, 0.f, 0.f, 0.f};

    const int ar = t >> 2;
    const int ac = (t & 3) * 8;
    const int bk = t >> 3;
    const int bn = (t & 7) * 8;

    __syncthreads();
    const bool in_f32 = (s_f32 != 0);
    const bool a_f32  = in_f32 && (a_dyn != 0);
    const bool c_f32  = in_f32 && (c_dyn != 0);

    for (int k0 = 0; k0 < Kd; k0 += 32) {
        __syncthreads();
        if (a_f32) {
            const float* Af = (const float*)A;
            const float4* pa = (const float4*)(Af + (size_t)(m0 + ar) * Kd + k0 + ac);
            float4 a0 = pa[0], a1 = pa[1];
            unsigned short* d = &As[ar][ac];
            d[0] = f2bf(a0.x); d[1] = f2bf(a0.y); d[2] = f2bf(a0.z); d[3] = f2bf(a0.w);
            d[4] = f2bf(a1.x); d[5] = f2bf(a1.y); d[6] = f2bf(a1.z); d[7] = f2bf(a1.w);
        } else {
            const unsigned short* Au = (const unsigned short*)A;
            uint4 av = *(const uint4*)(Au + (size_t)(m0 + ar) * Kd + k0 + ac);
            *(uint4*)(&As[ar][ac]) = av;
        }
        if (in_f32) {
            const float* Bf = (const float*)B;
            const float4* pb = (const float4*)(Bf + (size_t)(k0 + bk) * N + n0 + bn);
            float4 b0 = pb[0], b1 = pb[1];
            Bs[bn + 0][bk] = f2bf(b0.x); Bs[bn + 1][bk] = f2bf(b0.y);
            Bs[bn + 2][bk] = f2bf(b0.z); Bs[bn + 3][bk] = f2bf(b0.w);
            Bs[bn + 4][bk] = f2bf(b1.x); Bs[bn + 5][bk] = f2bf(b1.y);
            Bs[bn + 6][bk] = f2bf(b1.z); Bs[bn + 7][bk] = f2bf(b1.w);
        } else {
            const unsigned short* Bu = (const unsigned short*)B;
            uint4 bv = *(const uint4*)(Bu + (size_t)(k0 + bk) * N + n0 + bn);
            union { uint4 v; unsigned short s[8]; } bu; bu.v = bv;
            #pragma unroll
            for (int j = 0; j < 8; ++j) Bs[bn + j][bk] = bu.s[j];
        }
        __syncthreads();

        bf8_t va0 = *reinterpret_cast<const bf8_t*>(&As[wm * 32 + 0  + lr][quad * 8]);
        bf8_t va1 = *reinterpret_cast<const bf8_t*>(&As[wm * 32 + 16 + lr][quad * 8]);
        bf8_t vb0 = *reinterpret_cast<const bf8_t*>(&Bs[wn * 32 + 0  + lr][quad * 8]);
        bf8_t vb1 = *reinterpret_cast<const bf8_t*>(&Bs[wn * 32 + 16 + lr][quad * 8]);

        acc[0][0] = __builtin_amdgcn_mfma_f32_16x16x32_bf16(va0, vb0, acc[0][0], 0, 0, 0);
        acc[0][1] = __builtin_amdgcn_mfma_f32_16x16x32_bf16(va0, vb1, acc[0][1], 0, 0, 0);
        acc[1][0] = __builtin_amdgcn_mfma_f32_16x16x32_bf16(va1, vb0, acc[1][0], 0, 0, 0);
        acc[1][1] = __builtin_amdgcn_mfma_f32_16x16x32_bf16(va1, vb1, acc[1][1], 0, 0, 0);
    }

    if (c_trans) {
        // Ct[col][row] bf16, leading dim M; pack 4 consecutive rows -> ushort4
        #pragma unroll
        for (int mi = 0; mi < 2; ++mi)
            #pragma unroll
            for (int ni = 0; ni < 2; ++ni) {
                int row0 = m0 + wm * 32 + mi * 16 + quad * 4;
                int col  = n0 + wn * 32 + ni * 16 + lr;
                ushort4 v;
                v.x = f2bf(acc[mi][ni][0]); v.y = f2bf(acc[mi][ni][1]);
                v.z = f2bf(acc[mi][ni][2]); v.w = f2bf(acc[mi][ni][3]);
                *(ushort4*)((unsigned short*)C + (size_t)col * M + row0) = v;
            }
    } else {
        #pragma unroll
        for (int mi = 0; mi < 2; ++mi)
            #pragma unroll
            for (int ni = 0; ni < 2; ++ni)
                #pragma unroll
                for (int r = 0; r < 4; ++r) {
                    int row = m0 + wm * 32 + mi * 16 + quad * 4 + r;
                    int col = n0 + wn * 32 + ni * 16 + lr;
                    if (c_f32) ((float*)C)[(size_t)row * N + col] = acc[mi][ni][r];
                    else ((unsigned short*)C)[(size_t)row * N + col] = f2bf(acc[mi][ni][r]);
                }
    }
}

// ---------------------------------------------------------------------------
// RoPE in-place on [ROWS, nheads*128] bf16.
// ---------------------------------------------------------------------------
__global__ __launch_bounds__(64)
void rope_kernel(unsigned short* __restrict__ X, int nheads) {
    const int idx = blockIdx.x;
    const int h   = idx % nheads;
    const int row = idx / nheads;
    const int tpos = row % SEQ_T;
    const int i   = threadIdx.x;

    size_t base = (size_t)row * (nheads * HD) + h * HD;
    float inv = exp2f(-(float)i * (13.287712379549449f / 64.0f));
    float a = (float)tpos * inv;
    float s, c;
    sincosf(a, &s, &c);
    float x0 = bf2f(X[base + i]);
    float x1 = bf2f(X[base + i + 64]);
    X[base + i]      = f2bf(x0 * c - x1 * s);
    X[base + i + 64] = f2bf(x1 * c + x0 * s);
}

// ---------------------------------------------------------------------------
// MFMA sliding-window attention. Block = (b, h, 64-query tile), 4 waves,
// wave w owns queries [w*16, w*16+16). Keys in chunks of 32.
// Q: [ROWS,2048] bf16 (roped; O written in place). K: [ROWS,512] bf16 (roped).
// Vt: [512][ROWS] bf16 (V transposed: Vt[kvh*128+d][b*2048+pos]).
// S = Q K^T via mfma (A=Q row-major frag, B=K row-major frag).
// Softmax fully in registers (C-layout rows, shfl_xor over 16 lr-lanes).
// P -> per-wave LDS (bf16, A-layout) -> PV mfma with B=Vt frags.
// ---------------------------------------------------------------------------
#define QKS 136   // padded LDS stride for K rows (bank-safe, 16B aligned)
#define VTS 40    // padded LDS stride for Vt rows
#define PLS 40    // padded LDS stride for P rows

__global__ __launch_bounds__(256)
void attn_mfma(unsigned short* __restrict__ Q,
               const unsigned short* __restrict__ K,
               const unsigned short* __restrict__ Vt) {
    __shared__ unsigned short Ks[32][QKS];
    __shared__ unsigned short Vs[128][VTS];          // [d][key]
    __shared__ unsigned short Pl[4][16][PLS];        // per-wave private

    const int t    = threadIdx.x;
    const int b    = blockIdx.z;
    const int h    = blockIdx.y;
    const int q0   = blockIdx.x * 64;
    const int kvh  = h >> 2;
    const int w    = t >> 6;
    const int lane = t & 63;
    const int quad = lane >> 4;
    const int lr   = lane & 15;
    const float scale = 0.08838834764831845f;        // 1/sqrt(128)

    // Q fragments direct from global (L3-resident), reused over all chunks.
    // A-frag: lane holds Q[w*16+lr][kk*32+quad*8 .. +7]
    bf8_t qf[4];
    {
        const unsigned short* qrow = Q + (size_t)(b * SEQ_T + q0 + w * 16 + lr) * D_MODEL + h * HD;
        #pragma unroll
        for (int kk = 0; kk < 4; ++kk)
            qf[kk] = *(const bf8_t*)(qrow + kk * 32 + quad * 8);
    }

    f4_t O[8];
    #pragma unroll
    for (int dt = 0; dt < 8; ++dt) O[dt] = (f4_t){0.f, 0.f, 0.f, 0.f};
    float mrow[4] = {-1e30f, -1e30f, -1e30f, -1e30f};
    float lrow[4] = {0.f, 0.f, 0.f, 0.f};

    const int i_base = q0 + w * 16 + quad * 4;   // + r = query row (output layout)
    const int i_lo   = q0 + w * 16;
    const int i_hi   = i_lo + 15;

    int kb0 = q0 - WIN;
    if (kb0 < 0) kb0 = 0;

    for (int kb = kb0; kb <= q0 + 32; kb += 32) {
        __syncthreads();   // previous chunk's LDS reads done
        {   // stage K chunk [32][128] coalesced
            int r = t >> 3, c = (t & 7) * 16;
            const unsigned short* sk = K + (size_t)(b * SEQ_T + kb + r) * (NKVH * HD) + kvh * HD + c;
            *(uint4*)&Ks[r][c]     = *(const uint4*)sk;
            *(uint4*)&Ks[r][c + 8] = *(const uint4*)(sk + 8);
        }
        {   // stage Vt chunk [128 d][32 keys] (rows contiguous in key)
            int d = t >> 1, c = (t & 1) * 16;
            const unsigned short* sv = Vt + (size_t)(kvh * HD + d) * ROWS + b * SEQ_T + kb + c;
            *(uint4*)&Vs[d][c]     = *(const uint4*)sv;
            *(uint4*)&Vs[d][c + 8] = *(const uint4*)(sv + 8);
        }
        __syncthreads();

        // wave-uniform skip of fully-masked chunks (barriers already passed)
        if ((kb > i_hi) || (kb + 31 < i_lo - (WIN - 1))) continue;

        // ---- QK^T: S[16 q][32 k] per wave, two 16-col tiles ----
        f4_t s0 = (f4_t){0.f, 0.f, 0.f, 0.f};
        f4_t s1 = (f4_t){0.f, 0.f, 0.f, 0.f};
        #pragma unroll
        for (int kk = 0; kk < 4; ++kk) {
            bf8_t kf0 = *(const bf8_t*)&Ks[lr][kk * 32 + quad * 8];
            bf8_t kf1 = *(const bf8_t*)&Ks[16 + lr][kk * 32 + quad * 8];
            s0 = __builtin_amdgcn_mfma_f32_16x16x32_bf16(qf[kk], kf0, s0, 0, 0, 0);
            s1 = __builtin_amdgcn_mfma_f32_16x16x32_bf16(qf[kk], kf1, s1, 0, 0, 0);
        }

        // ---- mask + scale (C layout: row=i_base+r, col j) ----
        const int j0 = kb + lr, j1 = kb + 16 + lr;
        float sv0[4], sv1[4];
        bool ok0[4], ok1[4];
        #pragma unroll
        for (int r = 0; r < 4; ++r) {
            int i = i_base + r;
            ok0[r] = (j0 <= i) && (i - j0 < WIN);
            ok1[r] = (j1 <= i) && (i - j1 < WIN);
            sv0[r] = ok0[r] ? s0[r] * scale : -1e30f;
            sv1[r] = ok1[r] ? s1[r] * scale : -1e30f;
        }

        // ---- row max across the 16 lr-lanes (register shuffle reduce) ----
        float rmax[4];
        #pragma unroll
        for (int r = 0; r < 4; ++r) rmax[r] = fmaxf(sv0[r], sv1[r]);
        #pragma unroll
        for (int off = 1; off < 16; off <<= 1)
            #pragma unroll
            for (int r = 0; r < 4; ++r)
                rmax[r] = fmaxf(rmax[r], __shfl_xor(rmax[r], off));

        float alpha[4], p0[4], p1[4], rsum[4];
        #pragma unroll
        for (int r = 0; r < 4; ++r) {
            float mn = fmaxf(mrow[r], rmax[r]);
            alpha[r] = __expf(mrow[r] - mn);
            mrow[r]  = mn;
            p0[r] = ok0[r] ? __expf(sv0[r] - mn) : 0.f;
            p1[r] = ok1[r] ? __expf(sv1[r] - mn) : 0.f;
            rsum[r] = p0[r] + p1[r];
        }
        #pragma unroll
        for (int off = 1; off < 16; off <<= 1)
            #pragma unroll
            for (int r = 0; r < 4; ++r)
                rsum[r] += __shfl_xor(rsum[r], off);
        #pragma unroll
        for (int r = 0; r < 4; ++r) lrow[r] = lrow[r] * alpha[r] + rsum[r];

        // rescale O accumulators (same r <-> row mapping as S)
        #pragma unroll
        for (int dt = 0; dt < 8; ++dt)
            #pragma unroll
            for (int r = 0; r < 4; ++r)
                O[dt][r] *= alpha[r];

        // ---- P to per-wave LDS (C layout -> A layout), wave-local ----
        #pragma unroll
        for (int r = 0; r < 4; ++r) {
            Pl[w][quad * 4 + r][lr]      = f2bf(p0[r]);
            Pl[w][quad * 4 + r][16 + lr] = f2bf(p1[r]);
        }
        bf8_t pf = *(const bf8_t*)&Pl[w][lr][quad * 8];   // A[m=lr][k=quad*8+j]

        // ---- PV: O[16 q][128 d] += P[16][32] * V[32][128] ----
        #pragma unroll
        for (int dt = 0; dt < 8; ++dt) {
            bf8_t vf = *(const bf8_t*)&Vs[dt * 16 + lr][quad * 8];  // B[k=key][n=d]
            O[dt] = __builtin_amdgcn_mfma_f32_16x16x32_bf16(pf, vf, O[dt], 0, 0, 0);
        }
    }

    // ---- epilogue: normalize, store O in place over Q ----
    float invl[4];
    #pragma unroll
    for (int r = 0; r < 4; ++r) invl[r] = 1.0f / lrow[r];
    #pragma unroll
    for (int dt = 0; dt < 8; ++dt)
        #pragma unroll
        for (int r = 0; r < 4; ++r)
            Q[(size_t)(b * SEQ_T + i_base + r) * D_MODEL + h * HD + dt * 16 + lr] =
                f2bf(O[dt][r] * invl[r]);
}

// ---------------------------------------------------------------------------
extern "C" void kernel_launch(void* const* d_in, const int* in_sizes, int n_in,
                              void* d_out, int out_size, void* d_ws, size_t ws_size,
                              hipStream_t stream) {
    const void* x  = d_in[0];
    const void* Wq = d_in[1];
    const void* Wk = d_in[2];
    const void* Wv = d_in[3];
    const void* Wo = d_in[4];
    const unsigned short* sniffp = (const unsigned short*)d_in[1];

    // Workspace (bf16, 24 MB): Q[4096*2048] K[4096*512] Vt[512*4096]
    unsigned short* Qb  = (unsigned short*)d_ws;
    unsigned short* Kb  = Qb + (size_t)ROWS * D_MODEL;
    unsigned short* Vtb = Kb + (size_t)ROWS * (NKVH * HD);

    dim3 blk(256);
    // Q = x @ Wq
    gemm_dual<<<dim3(D_MODEL / 64, ROWS / 64), blk, 0, stream>>>(
        x, Wq, Qb, ROWS, D_MODEL, D_MODEL, sniffp, 1, 0, 0);
    // K = x @ Wk
    gemm_dual<<<dim3((NKVH * HD) / 64, ROWS / 64), blk, 0, stream>>>(
        x, Wk, Kb, ROWS, NKVH * HD, D_MODEL, sniffp, 1, 0, 0);
    // Vt = (x @ Wv)^T   (transposed store: Vt[n][row])
    gemm_dual<<<dim3((NKVH * HD) / 64, ROWS / 64), blk, 0, stream>>>(
        x, Wv, Vtb, ROWS, NKVH * HD, D_MODEL, sniffp, 1, 0, 1);
    // RoPE on Q and K
    rope_kernel<<<dim3(ROWS * NQH), dim3(64), 0, stream>>>(Qb, NQH);
    rope_kernel<<<dim3(ROWS * NKVH), dim3(64), 0, stream>>>(Kb, NKVH);
    // Attention (MFMA): O overwrites Q in place
    attn_mfma<<<dim3(SEQ_T / 64, NQH, BATCH), dim3(256), 0, stream>>>(Qb, Kb, Vtb);
    // out = O @ Wo
    gemm_dual<<<dim3(D_MODEL / 64, ROWS / 64), blk, 0, stream>>>(
        Qb, Wo, d_out, ROWS, D_MODEL, D_MODEL, sniffp, 0, 1, 0);
}

// Round 4
// 356.404 us; speedup vs baseline: 3.6665x; 1.9292x over previous
//
#include <hip/hip_runtime.h>
#include <hip/hip_bf16.h>

// Problem constants (match reference)
#define D_MODEL 2048
#define SEQ_T   2048
#define NQH     16
#define NKVH    4
#define HD      128
#define WIN     256
#define BATCH   2
#define ROWS    (BATCH * SEQ_T)   // 4096

typedef __attribute__((ext_vector_type(8))) short bf8_t;   // 8 bf16 in 4 VGPRs
typedef __attribute__((ext_vector_type(4))) float f4_t;    // MFMA acc

__device__ __forceinline__ float bf2f(unsigned short u) {
    union { unsigned int i; float f; } v; v.i = ((unsigned int)u) << 16; return v.f;
}
__device__ __forceinline__ unsigned short f2bf(float f) {
    union { float f; unsigned int i; } v; v.f = f;
    unsigned int x = v.i;
    unsigned int lsb = (x >> 16) & 1u;
    x += 0x7fffu + lsb;           // round-to-nearest-even (finite values only)
    return (unsigned short)(x >> 16);
}

// async global->LDS, 16B per lane; LDS dest = uniform base + lane*16.
__device__ __forceinline__ void async_ld16(const unsigned short* g, unsigned short* l) {
    __builtin_amdgcn_global_load_lds(
        (const __attribute__((address_space(1))) unsigned int*)(g),
        (__attribute__((address_space(3))) unsigned int*)(l), 16, 0, 0);
}

// Dtype sniff (kept for the fallback path only; inputs measured fp32).
__device__ int sniff_is_f32(const unsigned short* p) {
    int sane = 0;
    for (int i = 0; i < 64; ++i) {
        unsigned short u = p[2 * i];
        int e = (u >> 7) & 0xFF;
        sane += (e >= 100 && e <= 140) ? 1 : 0;
    }
    return sane < 32;
}

// ---------------------------------------------------------------------------
// convert_x: fp32 [n] -> bf16 [n], 8 elems/thread, streaming.
// ---------------------------------------------------------------------------
__global__ __launch_bounds__(256)
void convert_x(const float* __restrict__ x, unsigned short* __restrict__ xb) {
    int i = (blockIdx.x * 256 + threadIdx.x) * 8;
    float4 a = *(const float4*)(x + i);
    float4 b = *(const float4*)(x + i + 4);
    ushort4 o0, o1;
    o0.x = f2bf(a.x); o0.y = f2bf(a.y); o0.z = f2bf(a.z); o0.w = f2bf(a.w);
    o1.x = f2bf(b.x); o1.y = f2bf(b.y); o1.z = f2bf(b.z); o1.w = f2bf(b.w);
    *(ushort4*)(xb + i)     = o0;
    *(ushort4*)(xb + i + 4) = o1;
}

// ---------------------------------------------------------------------------
// convert_w_t: W[K][N] fp32 -> Wt[N][K] bf16 (transpose via LDS 32x32 tile).
// grid = (N/32, K/32), block = 256.
// ---------------------------------------------------------------------------
__global__ __launch_bounds__(256)
void convert_w_t(const float* __restrict__ W, unsigned short* __restrict__ Wt,
                 int K, int N) {
    __shared__ unsigned short Ts[32][36];
    const int n0 = blockIdx.x * 32;
    const int k0 = blockIdx.y * 32;
    const int t  = threadIdx.x;
    {
        int r = t >> 3, c = (t & 7) * 4;
        float4 v = *(const float4*)(W + (size_t)(k0 + r) * N + n0 + c);
        Ts[r][c + 0] = f2bf(v.x); Ts[r][c + 1] = f2bf(v.y);
        Ts[r][c + 2] = f2bf(v.z); Ts[r][c + 3] = f2bf(v.w);
    }
    __syncthreads();
    {
        int n = t >> 3, k = (t & 7) * 4;
        ushort4 o;
        o.x = Ts[k + 0][n]; o.y = Ts[k + 1][n];
        o.z = Ts[k + 2][n]; o.w = Ts[k + 3][n];
        *(ushort4*)(Wt + (size_t)(n0 + n) * K + k0 + k) = o;
    }
}

// ---------------------------------------------------------------------------
// gemm_bt128: C = A * Bt^T. A[M][K] bf16 k-major, Bt[N][K] bf16 k-major.
// m97 structure: 128x128 tile, BK=32, both tiles via global_load_lds w=16,
// 8 ds_read_b128 + 16 MFMA per K-step, 2 barriers.
// mode 0: C0 bf16 row-major [M][N]
// mode 1: C0 fp32 row-major [M][N]
// mode 2: fused KV epilogue: n<512 -> C0=Kb bf16 [M][512];
//         n>=512 -> C2=Vt bf16 [512][M] (transposed store).
// ---------------------------------------------------------------------------
__global__ __launch_bounds__(256)
void gemm_bt128(const unsigned short* __restrict__ A,
                const unsigned short* __restrict__ Bt,
                void* __restrict__ C0, void* __restrict__ C2,
                int M, int N, int K, int mode) {
    __shared__ unsigned short As[128 * 32];
    __shared__ unsigned short Bs[128 * 32];

    const int t    = threadIdx.x;
    const int w    = t >> 6;
    const int lane = t & 63;
    const int quad = lane >> 4;
    const int lr   = lane & 15;
    const int wm   = (w >> 1) * 64;
    const int wn   = (w & 1) * 64;
    const int m0   = blockIdx.y * 128;
    const int n0   = blockIdx.x * 128;

    const int grow = lane >> 2;        // 0..15: row within 16-row chunk
    const int gcol = (lane & 3) * 8;   // 0,8,16,24: k element

    f4_t acc[4][4];
    #pragma unroll
    for (int i = 0; i < 4; ++i)
        #pragma unroll
        for (int j = 0; j < 4; ++j)
            acc[i][j] = (f4_t){0.f, 0.f, 0.f, 0.f};

    for (int k0 = 0; k0 < K; k0 += 32) {
        __syncthreads();   // previous iter's ds_reads done
        #pragma unroll
        for (int cc = 0; cc < 2; ++cc) {
            const int chunk = w + cc * 4;  // wave-uniform
            async_ld16(A  + (size_t)(m0 + chunk * 16 + grow) * K + k0 + gcol,
                       &As[chunk * 512]);
            async_ld16(Bt + (size_t)(n0 + chunk * 16 + grow) * K + k0 + gcol,
                       &Bs[chunk * 512]);
        }
        __syncthreads();   // staging complete (vmcnt drain)

        bf8_t af[4], bfr[4];
        #pragma unroll
        for (int i = 0; i < 4; ++i) {
            af[i]  = *(const bf8_t*)&As[(wm + i * 16 + lr) * 32 + quad * 8];
            bfr[i] = *(const bf8_t*)&Bs[(wn + i * 16 + lr) * 32 + quad * 8];
        }
        #pragma unroll
        for (int i = 0; i < 4; ++i)
            #pragma unroll
            for (int j = 0; j < 4; ++j)
                acc[i][j] = __builtin_amdgcn_mfma_f32_16x16x32_bf16(af[i], bfr[j], acc[i][j], 0, 0, 0);
    }

    // Epilogue. D layout: col = lr, row = quad*4 + r (within each 16x16).
    if (mode == 0) {
        unsigned short* C = (unsigned short*)C0;
        #pragma unroll
        for (int i = 0; i < 4; ++i)
            #pragma unroll
            for (int j = 0; j < 4; ++j)
                #pragma unroll
                for (int r = 0; r < 4; ++r) {
                    int row = m0 + wm + i * 16 + quad * 4 + r;
                    int col = n0 + wn + j * 16 + lr;
                    C[(size_t)row * N + col] = f2bf(acc[i][j][r]);
                }
    } else if (mode == 1) {
        float* C = (float*)C0;
        #pragma unroll
        for (int i = 0; i < 4; ++i)
            #pragma unroll
            for (int j = 0; j < 4; ++j)
                #pragma unroll
                for (int r = 0; r < 4; ++r) {
                    int row = m0 + wm + i * 16 + quad * 4 + r;
                    int col = n0 + wn + j * 16 + lr;
                    C[(size_t)row * N + col] = acc[i][j][r];
                }
    } else {
        // fused KV: whole block lies in one half (512 % 128 == 0)
        if (n0 < 512) {
            unsigned short* Kb = (unsigned short*)C0;
            #pragma unroll
            for (int i = 0; i < 4; ++i)
                #pragma unroll
                for (int j = 0; j < 4; ++j)
                    #pragma unroll
                    for (int r = 0; r < 4; ++r) {
                        int row = m0 + wm + i * 16 + quad * 4 + r;
                        int col = n0 + wn + j * 16 + lr;
                        Kb[(size_t)row * 512 + col] = f2bf(acc[i][j][r]);
                    }
        } else {
            unsigned short* Vt = (unsigned short*)C2;
            #pragma unroll
            for (int i = 0; i < 4; ++i)
                #pragma unroll
                for (int j = 0; j < 4; ++j) {
                    int row0 = m0 + wm + i * 16 + quad * 4;
                    int n    = (n0 - 512) + wn + j * 16 + lr;
                    ushort4 o;
                    o.x = f2bf(acc[i][j][0]); o.y = f2bf(acc[i][j][1]);
                    o.z = f2bf(acc[i][j][2]); o.w = f2bf(acc[i][j][3]);
                    *(ushort4*)(Vt + (size_t)n * ROWS + row0) = o;
                }
        }
    }
}

// ---------------------------------------------------------------------------
// Fallback small-tile GEMM (round-3 path, used only if ws_size < 32 MB).
// ---------------------------------------------------------------------------
__global__ __launch_bounds__(256)
void gemm_dual(const void* __restrict__ A, const void* __restrict__ B,
               void* __restrict__ C, int M, int N, int Kd,
               const unsigned short* __restrict__ sniffp,
               int a_dyn, int c_dyn, int c_trans) {
    __shared__ unsigned short As[64][32];
    __shared__ unsigned short Bs[64][32];
    __shared__ int s_f32;

    const int t = threadIdx.x;
    if (t == 0) s_f32 = sniff_is_f32(sniffp);

    const int m0 = blockIdx.y * 64, n0 = blockIdx.x * 64;
    const int w = t >> 6, lane = t & 63;
    const int wm = w >> 1, wn = w & 1;
    const int quad = lane >> 4, lr = lane & 15;

    f4_t acc[2][2];
    #pragma unroll
    for (int i = 0; i < 2; ++i)
        #pragma unroll
        for (int j = 0; j < 2; ++j)
            acc[i][j] = (f4_t){0.f, 0.f, 0.f, 0.f};

    const int ar = t >> 2, ac = (t & 3) * 8;
    const int bk = t >> 3, bn = (t & 7) * 8;

    __syncthreads();
    const bool in_f32 = (s_f32 != 0);
    const bool a_f32  = in_f32 && (a_dyn != 0);
    const bool c_f32  = in_f32 && (c_dyn != 0);

    for (int k0 = 0; k0 < Kd; k0 += 32) {
        __syncthreads();
        if (a_f32) {
            const float* Af = (const float*)A;
            const float4* pa = (const float4*)(Af + (size_t)(m0 + ar) * Kd + k0 + ac);
            float4 a0 = pa[0], a1 = pa[1];
            unsigned short* d = &As[ar][ac];
            d[0] = f2bf(a0.x); d[1] = f2bf(a0.y); d[2] = f2bf(a0.z); d[3] = f2bf(a0.w);
            d[4] = f2bf(a1.x); d[5] = f2bf(a1.y); d[6] = f2bf(a1.z); d[7] = f2bf(a1.w);
        } else {
            const unsigned short* Au = (const unsigned short*)A;
            *(uint4*)(&As[ar][ac]) = *(const uint4*)(Au + (size_t)(m0 + ar) * Kd + k0 + ac);
        }
        if (in_f32) {
            const float* Bf = (const float*)B;
            const float4* pb = (const float4*)(Bf + (size_t)(k0 + bk) * N + n0 + bn);
            float4 b0 = pb[0], b1 = pb[1];
            Bs[bn + 0][bk] = f2bf(b0.x); Bs[bn + 1][bk] = f2bf(b0.y);
            Bs[bn + 2][bk] = f2bf(b0.z); Bs[bn + 3][bk] = f2bf(b0.w);
            Bs[bn + 4][bk] = f2bf(b1.x); Bs[bn + 5][bk] = f2bf(b1.y);
            Bs[bn + 6][bk] = f2bf(b1.z); Bs[bn + 7][bk] = f2bf(b1.w);
        } else {
            const unsigned short* Bu = (const unsigned short*)B;
            uint4 bv = *(const uint4*)(Bu + (size_t)(k0 + bk) * N + n0 + bn);
            union { uint4 v; unsigned short s[8]; } bu; bu.v = bv;
            #pragma unroll
            for (int j = 0; j < 8; ++j) Bs[bn + j][bk] = bu.s[j];
        }
        __syncthreads();

        bf8_t va0 = *(const bf8_t*)&As[wm * 32 + 0  + lr][quad * 8];
        bf8_t va1 = *(const bf8_t*)&As[wm * 32 + 16 + lr][quad * 8];
        bf8_t vb0 = *(const bf8_t*)&Bs[wn * 32 + 0  + lr][quad * 8];
        bf8_t vb1 = *(const bf8_t*)&Bs[wn * 32 + 16 + lr][quad * 8];

        acc[0][0] = __builtin_amdgcn_mfma_f32_16x16x32_bf16(va0, vb0, acc[0][0], 0, 0, 0);
        acc[0][1] = __builtin_amdgcn_mfma_f32_16x16x32_bf16(va0, vb1, acc[0][1], 0, 0, 0);
        acc[1][0] = __builtin_amdgcn_mfma_f32_16x16x32_bf16(va1, vb0, acc[1][0], 0, 0, 0);
        acc[1][1] = __builtin_amdgcn_mfma_f32_16x16x32_bf16(va1, vb1, acc[1][1], 0, 0, 0);
    }

    if (c_trans) {
        #pragma unroll
        for (int mi = 0; mi < 2; ++mi)
            #pragma unroll
            for (int ni = 0; ni < 2; ++ni) {
                int row0 = m0 + wm * 32 + mi * 16 + quad * 4;
                int col  = n0 + wn * 32 + ni * 16 + lr;
                ushort4 v;
                v.x = f2bf(acc[mi][ni][0]); v.y = f2bf(acc[mi][ni][1]);
                v.z = f2bf(acc[mi][ni][2]); v.w = f2bf(acc[mi][ni][3]);
                *(ushort4*)((unsigned short*)C + (size_t)col * M + row0) = v;
            }
    } else {
        #pragma unroll
        for (int mi = 0; mi < 2; ++mi)
            #pragma unroll
            for (int ni = 0; ni < 2; ++ni)
                #pragma unroll
                for (int r = 0; r < 4; ++r) {
                    int row = m0 + wm * 32 + mi * 16 + quad * 4 + r;
                    int col = n0 + wn * 32 + ni * 16 + lr;
                    if (c_f32) ((float*)C)[(size_t)row * N + col] = acc[mi][ni][r];
                    else ((unsigned short*)C)[(size_t)row * N + col] = f2bf(acc[mi][ni][r]);
                }
    }
}

// ---------------------------------------------------------------------------
// RoPE in-place on [ROWS, nheads*128] bf16.
// ---------------------------------------------------------------------------
__global__ __launch_bounds__(64)
void rope_kernel(unsigned short* __restrict__ X, int nheads) {
    const int idx = blockIdx.x;
    const int h   = idx % nheads;
    const int row = idx / nheads;
    const int tpos = row % SEQ_T;
    const int i   = threadIdx.x;

    size_t base = (size_t)row * (nheads * HD) + h * HD;
    float inv = exp2f(-(float)i * (13.287712379549449f / 64.0f));
    float a = (float)tpos * inv;
    float s, c;
    sincosf(a, &s, &c);
    float x0 = bf2f(X[base + i]);
    float x1 = bf2f(X[base + i + 64]);
    X[base + i]      = f2bf(x0 * c - x1 * s);
    X[base + i + 64] = f2bf(x1 * c + x0 * s);
}

// ---------------------------------------------------------------------------
// MFMA sliding-window attention (unchanged from round 3).
// ---------------------------------------------------------------------------
#define QKS 136
#define VTS 40
#define PLS 40

__global__ __launch_bounds__(256)
void attn_mfma(unsigned short* __restrict__ Q,
               const unsigned short* __restrict__ K,
               const unsigned short* __restrict__ Vt) {
    __shared__ unsigned short Ks[32][QKS];
    __shared__ unsigned short Vs[128][VTS];
    __shared__ unsigned short Pl[4][16][PLS];

    const int t    = threadIdx.x;
    const int b    = blockIdx.z;
    const int h    = blockIdx.y;
    const int q0   = blockIdx.x * 64;
    const int kvh  = h >> 2;
    const int w    = t >> 6;
    const int lane = t & 63;
    const int quad = lane >> 4;
    const int lr   = lane & 15;
    const float scale = 0.08838834764831845f;

    bf8_t qf[4];
    {
        const unsigned short* qrow = Q + (size_t)(b * SEQ_T + q0 + w * 16 + lr) * D_MODEL + h * HD;
        #pragma unroll
        for (int kk = 0; kk < 4; ++kk)
            qf[kk] = *(const bf8_t*)(qrow + kk * 32 + quad * 8);
    }

    f4_t O[8];
    #pragma unroll
    for (int dt = 0; dt < 8; ++dt) O[dt] = (f4_t){0.f, 0.f, 0.f, 0.f};
    float mrow[4] = {-1e30f, -1e30f, -1e30f, -1e30f};
    float lrow[4] = {0.f, 0.f, 0.f, 0.f};

    const int i_base = q0 + w * 16 + quad * 4;
    const int i_lo   = q0 + w * 16;
    const int i_hi   = i_lo + 15;

    int kb0 = q0 - WIN;
    if (kb0 < 0) kb0 = 0;

    for (int kb = kb0; kb <= q0 + 32; kb += 32) {
        __syncthreads();
        {
            int r = t >> 3, c = (t & 7) * 16;
            const unsigned short* sk = K + (size_t)(b * SEQ_T + kb + r) * (NKVH * HD) + kvh * HD + c;
            *(uint4*)&Ks[r][c]     = *(const uint4*)sk;
            *(uint4*)&Ks[r][c + 8] = *(const uint4*)(sk + 8);
        }
        {
            int d = t >> 1, c = (t & 1) * 16;
            const unsigned short* sv = Vt + (size_t)(kvh * HD + d) * ROWS + b * SEQ_T + kb + c;
            *(uint4*)&Vs[d][c]     = *(const uint4*)sv;
            *(uint4*)&Vs[d][c + 8] = *(const uint4*)(sv + 8);
        }
        __syncthreads();

        if ((kb > i_hi) || (kb + 31 < i_lo - (WIN - 1))) continue;

        f4_t s0 = (f4_t){0.f, 0.f, 0.f, 0.f};
        f4_t s1 = (f4_t){0.f, 0.f, 0.f, 0.f};
        #pragma unroll
        for (int kk = 0; kk < 4; ++kk) {
            bf8_t kf0 = *(const bf8_t*)&Ks[lr][kk * 32 + quad * 8];
            bf8_t kf1 = *(const bf8_t*)&Ks[16 + lr][kk * 32 + quad * 8];
            s0 = __builtin_amdgcn_mfma_f32_16x16x32_bf16(qf[kk], kf0, s0, 0, 0, 0);
            s1 = __builtin_amdgcn_mfma_f32_16x16x32_bf16(qf[kk], kf1, s1, 0, 0, 0);
        }

        const int j0 = kb + lr, j1 = kb + 16 + lr;
        float sv0[4], sv1[4];
        bool ok0[4], ok1[4];
        #pragma unroll
        for (int r = 0; r < 4; ++r) {
            int i = i_base + r;
            ok0[r] = (j0 <= i) && (i - j0 < WIN);
            ok1[r] = (j1 <= i) && (i - j1 < WIN);
            sv0[r] = ok0[r] ? s0[r] * scale : -1e30f;
            sv1[r] = ok1[r] ? s1[r] * scale : -1e30f;
        }

        float rmax[4];
        #pragma unroll
        for (int r = 0; r < 4; ++r) rmax[r] = fmaxf(sv0[r], sv1[r]);
        #pragma unroll
        for (int off = 1; off < 16; off <<= 1)
            #pragma unroll
            for (int r = 0; r < 4; ++r)
                rmax[r] = fmaxf(rmax[r], __shfl_xor(rmax[r], off));

        float alpha[4], p0[4], p1[4], rsum[4];
        #pragma unroll
        for (int r = 0; r < 4; ++r) {
            float mn = fmaxf(mrow[r], rmax[r]);
            alpha[r] = __expf(mrow[r] - mn);
            mrow[r]  = mn;
            p0[r] = ok0[r] ? __expf(sv0[r] - mn) : 0.f;
            p1[r] = ok1[r] ? __expf(sv1[r] - mn) : 0.f;
            rsum[r] = p0[r] + p1[r];
        }
        #pragma unroll
        for (int off = 1; off < 16; off <<= 1)
            #pragma unroll
            for (int r = 0; r < 4; ++r)
                rsum[r] += __shfl_xor(rsum[r], off);
        #pragma unroll
        for (int r = 0; r < 4; ++r) lrow[r] = lrow[r] * alpha[r] + rsum[r];

        #pragma unroll
        for (int dt = 0; dt < 8; ++dt)
            #pragma unroll
            for (int r = 0; r < 4; ++r)
                O[dt][r] *= alpha[r];

        #pragma unroll
        for (int r = 0; r < 4; ++r) {
            Pl[w][quad * 4 + r][lr]      = f2bf(p0[r]);
            Pl[w][quad * 4 + r][16 + lr] = f2bf(p1[r]);
        }
        bf8_t pf = *(const bf8_t*)&Pl[w][lr][quad * 8];

        #pragma unroll
        for (int dt = 0; dt < 8; ++dt) {
            bf8_t vf = *(const bf8_t*)&Vs[dt * 16 + lr][quad * 8];
            O[dt] = __builtin_amdgcn_mfma_f32_16x16x32_bf16(pf, vf, O[dt], 0, 0, 0);
        }
    }

    float invl[4];
    #pragma unroll
    for (int r = 0; r < 4; ++r) invl[r] = 1.0f / lrow[r];
    #pragma unroll
    for (int dt = 0; dt < 8; ++dt)
        #pragma unroll
        for (int r = 0; r < 4; ++r)
            Q[(size_t)(b * SEQ_T + i_base + r) * D_MODEL + h * HD + dt * 16 + lr] =
                f2bf(O[dt][r] * invl[r]);
}

// ---------------------------------------------------------------------------
extern "C" void kernel_launch(void* const* d_in, const int* in_sizes, int n_in,
                              void* d_out, int out_size, void* d_ws, size_t ws_size,
                              hipStream_t stream) {
    const float* x  = (const float*)d_in[0];
    const float* Wq = (const float*)d_in[1];
    const float* Wk = (const float*)d_in[2];
    const float* Wv = (const float*)d_in[3];
    const float* Wo = (const float*)d_in[4];
    const unsigned short* sniffp = (const unsigned short*)d_in[1];

    // ws layout (fast path, 32 MB): Qb 16MB | Kb 4MB | Vtb 4MB | Wot 8MB
    unsigned short* Qb  = (unsigned short*)d_ws;
    unsigned short* Kb  = Qb + (size_t)ROWS * D_MODEL;
    unsigned short* Vtb = Kb + (size_t)ROWS * (NKVH * HD);
    unsigned short* Wot = Vtb + (size_t)(NKVH * HD) * ROWS;

    dim3 blk(256);

    if (ws_size >= (size_t)32 * 1024 * 1024) {
        // d_out doubles as scratch until the final GEMM (28 MB of 32 MB):
        //   xb 16MB | Wqt 8MB | Wkvt 4MB
        unsigned short* xb   = (unsigned short*)d_out;
        unsigned short* Wqt  = xb + (size_t)ROWS * D_MODEL;
        unsigned short* Wkvt = Wqt + (size_t)D_MODEL * D_MODEL;

        // --- converts ---
        convert_x<<<dim3(ROWS * D_MODEL / (256 * 8)), blk, 0, stream>>>(x, xb);
        convert_w_t<<<dim3(D_MODEL / 32, D_MODEL / 32), blk, 0, stream>>>(Wq, Wqt, D_MODEL, D_MODEL);
        convert_w_t<<<dim3((NKVH * HD) / 32, D_MODEL / 32), blk, 0, stream>>>(Wk, Wkvt, D_MODEL, NKVH * HD);
        convert_w_t<<<dim3((NKVH * HD) / 32, D_MODEL / 32), blk, 0, stream>>>(
            Wv, Wkvt + (size_t)(NKVH * HD) * D_MODEL, D_MODEL, NKVH * HD);
        convert_w_t<<<dim3(D_MODEL / 32, D_MODEL / 32), blk, 0, stream>>>(Wo, Wot, D_MODEL, D_MODEL);

        // --- projections (m97-style) ---
        gemm_bt128<<<dim3(D_MODEL / 128, ROWS / 128), blk, 0, stream>>>(
            xb, Wqt, Qb, nullptr, ROWS, D_MODEL, D_MODEL, 0);
        gemm_bt128<<<dim3((2 * NKVH * HD) / 128, ROWS / 128), blk, 0, stream>>>(
            xb, Wkvt, Kb, Vtb, ROWS, 2 * NKVH * HD, D_MODEL, 2);

        // --- RoPE ---
        rope_kernel<<<dim3(ROWS * NQH), dim3(64), 0, stream>>>(Qb, NQH);
        rope_kernel<<<dim3(ROWS * NKVH), dim3(64), 0, stream>>>(Kb, NKVH);

        // --- attention (O over Q in place) ---
        attn_mfma<<<dim3(SEQ_T / 64, NQH, BATCH), dim3(256), 0, stream>>>(Qb, Kb, Vtb);

        // --- out = O @ Wo (fp32 into d_out; xb/Wqt/Wkvt dead by now) ---
        gemm_bt128<<<dim3(D_MODEL / 128, ROWS / 128), blk, 0, stream>>>(
            Qb, Wot, d_out, nullptr, ROWS, D_MODEL, D_MODEL, 1);
    } else {
        // Fallback: round-3 path (24 MB ws)
        gemm_dual<<<dim3(D_MODEL / 64, ROWS / 64), blk, 0, stream>>>(
            x, Wq, Qb, ROWS, D_MODEL, D_MODEL, sniffp, 1, 0, 0);
        gemm_dual<<<dim3((NKVH * HD) / 64, ROWS / 64), blk, 0, stream>>>(
            x, Wk, Kb, ROWS, NKVH * HD, D_MODEL, sniffp, 1, 0, 0);
        gemm_dual<<<dim3((NKVH * HD) / 64, ROWS / 64), blk, 0, stream>>>(
            x, Wv, Vtb, ROWS, NKVH * HD, D_MODEL, sniffp, 1, 0, 1);
        rope_kernel<<<dim3(ROWS * NQH), dim3(64), 0, stream>>>(Qb, NQH);
        rope_kernel<<<dim3(ROWS * NKVH), dim3(64), 0, stream>>>(Kb, NKVH);
        attn_mfma<<<dim3(SEQ_T / 64, NQH, BATCH), dim3(256), 0, stream>>>(Qb, Kb, Vtb);
        gemm_dual<<<dim3(D_MODEL / 64, ROWS / 64), blk, 0, stream>>>(
            Qb, Wo, d_out, ROWS, D_MODEL, D_MODEL, sniffp, 0, 1, 0);
    }
}

// Round 5
// 304.106 us; speedup vs baseline: 4.2970x; 1.1720x over previous
//
#include <hip/hip_runtime.h>
#include <hip/hip_bf16.h>

// Problem constants (match reference)
#define D_MODEL 2048
#define SEQ_T   2048
#define NQH     16
#define NKVH    4
#define HD      128
#define WIN     256
#define BATCH   2
#define ROWS    (BATCH * SEQ_T)   // 4096
#define L2_10K  13.287712379549449f   // log2(10000)

typedef __attribute__((ext_vector_type(8))) short bf8_t;   // 8 bf16 in 4 VGPRs
typedef __attribute__((ext_vector_type(4))) float f4_t;    // MFMA acc

__device__ __forceinline__ float bf2f(unsigned short u) {
    union { unsigned int i; float f; } v; v.i = ((unsigned int)u) << 16; return v.f;
}
__device__ __forceinline__ unsigned short f2bf(float f) {
    union { float f; unsigned int i; } v; v.f = f;
    unsigned int x = v.i;
    unsigned int lsb = (x >> 16) & 1u;
    x += 0x7fffu + lsb;           // round-to-nearest-even (finite values only)
    return (unsigned short)(x >> 16);
}

// async global->LDS, 16B per lane; LDS dest = uniform base + lane*16.
__device__ __forceinline__ void async_ld16(const unsigned short* g, unsigned short* l) {
    __builtin_amdgcn_global_load_lds(
        (const __attribute__((address_space(1))) unsigned int*)(g),
        (__attribute__((address_space(3))) unsigned int*)(l), 16, 0, 0);
}

__device__ int sniff_is_f32(const unsigned short* p) {
    int sane = 0;
    for (int i = 0; i < 64; ++i) {
        unsigned short u = p[2 * i];
        int e = (u >> 7) & 0xFF;
        sane += (e >= 100 && e <= 140) ? 1 : 0;
    }
    return sane < 32;
}

// ---------------------------------------------------------------------------
// convert_x: fp32 [n] -> bf16 [n], 8 elems/thread, streaming.
// ---------------------------------------------------------------------------
__global__ __launch_bounds__(256)
void convert_x(const float* __restrict__ x, unsigned short* __restrict__ xb) {
    int i = (blockIdx.x * 256 + threadIdx.x) * 8;
    float4 a = *(const float4*)(x + i);
    float4 b = *(const float4*)(x + i + 4);
    ushort4 o0, o1;
    o0.x = f2bf(a.x); o0.y = f2bf(a.y); o0.z = f2bf(a.z); o0.w = f2bf(a.w);
    o1.x = f2bf(b.x); o1.y = f2bf(b.y); o1.z = f2bf(b.z); o1.w = f2bf(b.w);
    *(ushort4*)(xb + i)     = o0;
    *(ushort4*)(xb + i + 4) = o1;
}

// ---------------------------------------------------------------------------
// convert_w_t: W[K][N] fp32 -> Wt[N][K] bf16 (transpose via LDS 32x32 tile).
// ---------------------------------------------------------------------------
__global__ __launch_bounds__(256)
void convert_w_t(const float* __restrict__ W, unsigned short* __restrict__ Wt,
                 int K, int N) {
    __shared__ unsigned short Ts[32][36];
    const int n0 = blockIdx.x * 32;
    const int k0 = blockIdx.y * 32;
    const int t  = threadIdx.x;
    {
        int r = t >> 3, c = (t & 7) * 4;
        float4 v = *(const float4*)(W + (size_t)(k0 + r) * N + n0 + c);
        Ts[r][c + 0] = f2bf(v.x); Ts[r][c + 1] = f2bf(v.y);
        Ts[r][c + 2] = f2bf(v.z); Ts[r][c + 3] = f2bf(v.w);
    }
    __syncthreads();
    {
        int n = t >> 3, k = (t & 7) * 4;
        ushort4 o;
        o.x = Ts[k + 0][n]; o.y = Ts[k + 1][n];
        o.z = Ts[k + 2][n]; o.w = Ts[k + 3][n];
        *(ushort4*)(Wt + (size_t)(n0 + n) * K + k0 + k) = o;
    }
}

// ---------------------------------------------------------------------------
// gemm_bt128: C = A * Bt^T. A[M][K], Bt[N][K], both bf16 k-major.
// 128x128 tile, BK=64 (two 32-k sub-tiles per barrier pair), global_load_lds
// w=16 staging, interleaved column-tile mapping jj = wn + 2*j so RoPE pairs
// (d, d+64) are same-lane (acc[j] <-> acc[j+2]).
// mode 1: C fp32 row-major [M][N] (out-proj)
// mode 3: fused QKV epilogue with RoPE:
//   n0 <  2048          -> Cq bf16 [M][2048], roped
//   2048 <= n0 < 2560   -> Ck bf16 [M][512],  roped
//   n0 >= 2560          -> Cvt bf16 [512][M]  (transposed V, no rope)
// ---------------------------------------------------------------------------
__global__ __launch_bounds__(256)
void gemm_bt128(const unsigned short* __restrict__ A,
                const unsigned short* __restrict__ Bt,
                void* __restrict__ Cq, void* __restrict__ Ck,
                void* __restrict__ Cvt,
                int M, int N, int K, int mode) {
    __shared__ unsigned short As[2][128 * 32];
    __shared__ unsigned short Bs[2][128 * 32];

    const int t    = threadIdx.x;
    const int w    = t >> 6;
    const int lane = t & 63;
    const int quad = lane >> 4;
    const int lr   = lane & 15;
    const int wm   = (w >> 1) * 64;     // row offset of wave's 64-row strip
    const int wnb  = (w & 1);           // column interleave base
    const int m0   = blockIdx.y * 128;
    const int n0   = blockIdx.x * 128;

    const int grow = lane >> 2;        // 0..15: row within 16-row chunk
    const int gcol = (lane & 3) * 8;   // 0,8,16,24: k element

    f4_t acc[4][4];
    #pragma unroll
    for (int i = 0; i < 4; ++i)
        #pragma unroll
        for (int j = 0; j < 4; ++j)
            acc[i][j] = (f4_t){0.f, 0.f, 0.f, 0.f};

    for (int k0 = 0; k0 < K; k0 += 64) {
        __syncthreads();   // previous iter's ds_reads done
        #pragma unroll
        for (int s = 0; s < 2; ++s)
            #pragma unroll
            for (int cc = 0; cc < 2; ++cc) {
                const int c = w + cc * 4;  // wave-uniform chunk id
                async_ld16(A  + (size_t)(m0 + c * 16 + grow) * K + k0 + s * 32 + gcol,
                           &As[s][c * 512]);
                async_ld16(Bt + (size_t)(n0 + c * 16 + grow) * K + k0 + s * 32 + gcol,
                           &Bs[s][c * 512]);
            }
        __syncthreads();   // staging complete

        #pragma unroll
        for (int s = 0; s < 2; ++s) {
            bf8_t af[4], bfr[4];
            #pragma unroll
            for (int i = 0; i < 4; ++i)
                af[i]  = *(const bf8_t*)&As[s][(wm + i * 16 + lr) * 32 + quad * 8];
            #pragma unroll
            for (int j = 0; j < 4; ++j)
                bfr[j] = *(const bf8_t*)&Bs[s][(wnb * 16 + j * 32 + lr) * 32 + quad * 8];
            #pragma unroll
            for (int i = 0; i < 4; ++i)
                #pragma unroll
                for (int j = 0; j < 4; ++j)
                    acc[i][j] = __builtin_amdgcn_mfma_f32_16x16x32_bf16(af[i], bfr[j], acc[i][j], 0, 0, 0);
        }
    }

    // D layout per 16x16: col = lr, row = quad*4 + r. Wave's col for tile j:
    // n_local = wnb*16 + j*32 + lr  (j=0..3; pairs (j, j+2) differ by +64).
    if (mode == 1) {
        float* C = (float*)Cq;
        #pragma unroll
        for (int i = 0; i < 4; ++i)
            #pragma unroll
            for (int j = 0; j < 4; ++j) {
                int col = n0 + wnb * 16 + j * 32 + lr;
                #pragma unroll
                for (int r = 0; r < 4; ++r) {
                    int row = m0 + wm + i * 16 + quad * 4 + r;
                    C[(size_t)row * N + col] = acc[i][j][r];
                }
            }
    } else {
        if (n0 < 2048 + 512) {
            // Q or K region: apply RoPE. Tile (128 cols) == one head.
            const bool isQ = (n0 < 2048);
            unsigned short* Cb = isQ ? (unsigned short*)Cq : (unsigned short*)Ck;
            const int ldc   = isQ ? D_MODEL : (NKVH * HD);
            const int cbase = isQ ? n0 : (n0 - 2048);
            float inv[2];
            #pragma unroll
            for (int j = 0; j < 2; ++j) {
                int d = wnb * 16 + j * 32 + lr;            // 0..63
                inv[j] = exp2f(-(float)d * (L2_10K / 64.0f));
            }
            #pragma unroll
            for (int i = 0; i < 4; ++i)
                #pragma unroll
                for (int r = 0; r < 4; ++r) {
                    int row = m0 + wm + i * 16 + quad * 4 + r;
                    float tp = (float)(row & (SEQ_T - 1));
                    #pragma unroll
                    for (int j = 0; j < 2; ++j) {
                        int d = wnb * 16 + j * 32 + lr;
                        float sn, cs;
                        sincosf(tp * inv[j], &sn, &cs);
                        float lo = acc[i][j][r], hi = acc[i][j + 2][r];
                        Cb[(size_t)row * ldc + cbase + d]      = f2bf(lo * cs - hi * sn);
                        Cb[(size_t)row * ldc + cbase + d + 64] = f2bf(hi * cs + lo * sn);
                    }
                }
        } else {
            // V region: transposed store Vt[n][row], no rope.
            unsigned short* Vt = (unsigned short*)Cvt;
            #pragma unroll
            for (int i = 0; i < 4; ++i)
                #pragma unroll
                for (int j = 0; j < 4; ++j) {
                    int n    = (n0 - 2560) + wnb * 16 + j * 32 + lr;
                    int row0 = m0 + wm + i * 16 + quad * 4;
                    ushort4 o;
                    o.x = f2bf(acc[i][j][0]); o.y = f2bf(acc[i][j][1]);
                    o.z = f2bf(acc[i][j][2]); o.w = f2bf(acc[i][j][3]);
                    *(ushort4*)(Vt + (size_t)n * ROWS + row0) = o;
                }
        }
    }
}

// ---------------------------------------------------------------------------
// Fallback small-tile GEMM (used only if ws_size < 32 MiB).
// ---------------------------------------------------------------------------
__global__ __launch_bounds__(256)
void gemm_dual(const void* __restrict__ A, const void* __restrict__ B,
               void* __restrict__ C, int M, int N, int Kd,
               const unsigned short* __restrict__ sniffp,
               int a_dyn, int c_dyn, int c_trans) {
    __shared__ unsigned short As[64][32];
    __shared__ unsigned short Bs[64][32];
    __shared__ int s_f32;

    const int t = threadIdx.x;
    if (t == 0) s_f32 = sniff_is_f32(sniffp);

    const int m0 = blockIdx.y * 64, n0 = blockIdx.x * 64;
    const int w = t >> 6, lane = t & 63;
    const int wm = w >> 1, wn = w & 1;
    const int quad = lane >> 4, lr = lane & 15;

    f4_t acc[2][2];
    #pragma unroll
    for (int i = 0; i < 2; ++i)
        #pragma unroll
        for (int j = 0; j < 2; ++j)
            acc[i][j] = (f4_t){0.f, 0.f, 0.f, 0.f};

    const int ar = t >> 2, ac = (t & 3) * 8;
    const int bk = t >> 3, bn = (t & 7) * 8;

    __syncthreads();
    const bool in_f32 = (s_f32 != 0);
    const bool a_f32  = in_f32 && (a_dyn != 0);
    const bool c_f32  = in_f32 && (c_dyn != 0);

    for (int k0 = 0; k0 < Kd; k0 += 32) {
        __syncthreads();
        if (a_f32) {
            const float* Af = (const float*)A;
            const float4* pa = (const float4*)(Af + (size_t)(m0 + ar) * Kd + k0 + ac);
            float4 a0 = pa[0], a1 = pa[1];
            unsigned short* d = &As[ar][ac];
            d[0] = f2bf(a0.x); d[1] = f2bf(a0.y); d[2] = f2bf(a0.z); d[3] = f2bf(a0.w);
            d[4] = f2bf(a1.x); d[5] = f2bf(a1.y); d[6] = f2bf(a1.z); d[7] = f2bf(a1.w);
        } else {
            const unsigned short* Au = (const unsigned short*)A;
            *(uint4*)(&As[ar][ac]) = *(const uint4*)(Au + (size_t)(m0 + ar) * Kd + k0 + ac);
        }
        if (in_f32) {
            const float* Bf = (const float*)B;
            const float4* pb = (const float4*)(Bf + (size_t)(k0 + bk) * N + n0 + bn);
            float4 b0 = pb[0], b1 = pb[1];
            Bs[bn + 0][bk] = f2bf(b0.x); Bs[bn + 1][bk] = f2bf(b0.y);
            Bs[bn + 2][bk] = f2bf(b0.z); Bs[bn + 3][bk] = f2bf(b0.w);
            Bs[bn + 4][bk] = f2bf(b1.x); Bs[bn + 5][bk] = f2bf(b1.y);
            Bs[bn + 6][bk] = f2bf(b1.z); Bs[bn + 7][bk] = f2bf(b1.w);
        } else {
            const unsigned short* Bu = (const unsigned short*)B;
            uint4 bv = *(const uint4*)(Bu + (size_t)(k0 + bk) * N + n0 + bn);
            union { uint4 v; unsigned short s[8]; } bu; bu.v = bv;
            #pragma unroll
            for (int j = 0; j < 8; ++j) Bs[bn + j][bk] = bu.s[j];
        }
        __syncthreads();

        bf8_t va0 = *(const bf8_t*)&As[wm * 32 + 0  + lr][quad * 8];
        bf8_t va1 = *(const bf8_t*)&As[wm * 32 + 16 + lr][quad * 8];
        bf8_t vb0 = *(const bf8_t*)&Bs[wn * 32 + 0  + lr][quad * 8];
        bf8_t vb1 = *(const bf8_t*)&Bs[wn * 32 + 16 + lr][quad * 8];

        acc[0][0] = __builtin_amdgcn_mfma_f32_16x16x32_bf16(va0, vb0, acc[0][0], 0, 0, 0);
        acc[0][1] = __builtin_amdgcn_mfma_f32_16x16x32_bf16(va0, vb1, acc[0][1], 0, 0, 0);
        acc[1][0] = __builtin_amdgcn_mfma_f32_16x16x32_bf16(va1, vb0, acc[1][0], 0, 0, 0);
        acc[1][1] = __builtin_amdgcn_mfma_f32_16x16x32_bf16(va1, vb1, acc[1][1], 0, 0, 0);
    }

    if (c_trans) {
        #pragma unroll
        for (int mi = 0; mi < 2; ++mi)
            #pragma unroll
            for (int ni = 0; ni < 2; ++ni) {
                int row0 = m0 + wm * 32 + mi * 16 + quad * 4;
                int col  = n0 + wn * 32 + ni * 16 + lr;
                ushort4 v;
                v.x = f2bf(acc[mi][ni][0]); v.y = f2bf(acc[mi][ni][1]);
                v.z = f2bf(acc[mi][ni][2]); v.w = f2bf(acc[mi][ni][3]);
                *(ushort4*)((unsigned short*)C + (size_t)col * M + row0) = v;
            }
    } else {
        #pragma unroll
        for (int mi = 0; mi < 2; ++mi)
            #pragma unroll
            for (int ni = 0; ni < 2; ++ni)
                #pragma unroll
                for (int r = 0; r < 4; ++r) {
                    int row = m0 + wm * 32 + mi * 16 + quad * 4 + r;
                    int col = n0 + wn * 32 + ni * 16 + lr;
                    if (c_f32) ((float*)C)[(size_t)row * N + col] = acc[mi][ni][r];
                    else ((unsigned short*)C)[(size_t)row * N + col] = f2bf(acc[mi][ni][r]);
                }
    }
}

// ---------------------------------------------------------------------------
// RoPE in-place (fallback path only).
// ---------------------------------------------------------------------------
__global__ __launch_bounds__(64)
void rope_kernel(unsigned short* __restrict__ X, int nheads) {
    const int idx = blockIdx.x;
    const int h   = idx % nheads;
    const int row = idx / nheads;
    const int tpos = row % SEQ_T;
    const int i   = threadIdx.x;

    size_t base = (size_t)row * (nheads * HD) + h * HD;
    float inv = exp2f(-(float)i * (L2_10K / 64.0f));
    float a = (float)tpos * inv;
    float s, c;
    sincosf(a, &s, &c);
    float x0 = bf2f(X[base + i]);
    float x1 = bf2f(X[base + i + 64]);
    X[base + i]      = f2bf(x0 * c - x1 * s);
    X[base + i + 64] = f2bf(x1 * c + x0 * s);
}

// ---------------------------------------------------------------------------
// MFMA sliding-window attention (unchanged from round 3/4).
// ---------------------------------------------------------------------------
#define QKS 136
#define VTS 40
#define PLS 40

__global__ __launch_bounds__(256)
void attn_mfma(unsigned short* __restrict__ Q,
               const unsigned short* __restrict__ K,
               const unsigned short* __restrict__ Vt) {
    __shared__ unsigned short Ks[32][QKS];
    __shared__ unsigned short Vs[128][VTS];
    __shared__ unsigned short Pl[4][16][PLS];

    const int t    = threadIdx.x;
    const int b    = blockIdx.z;
    const int h    = blockIdx.y;
    const int q0   = blockIdx.x * 64;
    const int kvh  = h >> 2;
    const int w    = t >> 6;
    const int lane = t & 63;
    const int quad = lane >> 4;
    const int lr   = lane & 15;
    const float scale = 0.08838834764831845f;

    bf8_t qf[4];
    {
        const unsigned short* qrow = Q + (size_t)(b * SEQ_T + q0 + w * 16 + lr) * D_MODEL + h * HD;
        #pragma unroll
        for (int kk = 0; kk < 4; ++kk)
            qf[kk] = *(const bf8_t*)(qrow + kk * 32 + quad * 8);
    }

    f4_t O[8];
    #pragma unroll
    for (int dt = 0; dt < 8; ++dt) O[dt] = (f4_t){0.f, 0.f, 0.f, 0.f};
    float mrow[4] = {-1e30f, -1e30f, -1e30f, -1e30f};
    float lrow[4] = {0.f, 0.f, 0.f, 0.f};

    const int i_base = q0 + w * 16 + quad * 4;
    const int i_lo   = q0 + w * 16;
    const int i_hi   = i_lo + 15;

    int kb0 = q0 - WIN;
    if (kb0 < 0) kb0 = 0;

    for (int kb = kb0; kb <= q0 + 32; kb += 32) {
        __syncthreads();
        {
            int r = t >> 3, c = (t & 7) * 16;
            const unsigned short* sk = K + (size_t)(b * SEQ_T + kb + r) * (NKVH * HD) + kvh * HD + c;
            *(uint4*)&Ks[r][c]     = *(const uint4*)sk;
            *(uint4*)&Ks[r][c + 8] = *(const uint4*)(sk + 8);
        }
        {
            int d = t >> 1, c = (t & 1) * 16;
            const unsigned short* sv = Vt + (size_t)(kvh * HD + d) * ROWS + b * SEQ_T + kb + c;
            *(uint4*)&Vs[d][c]     = *(const uint4*)sv;
            *(uint4*)&Vs[d][c + 8] = *(const uint4*)(sv + 8);
        }
        __syncthreads();

        if ((kb > i_hi) || (kb + 31 < i_lo - (WIN - 1))) continue;

        f4_t s0 = (f4_t){0.f, 0.f, 0.f, 0.f};
        f4_t s1 = (f4_t){0.f, 0.f, 0.f, 0.f};
        #pragma unroll
        for (int kk = 0; kk < 4; ++kk) {
            bf8_t kf0 = *(const bf8_t*)&Ks[lr][kk * 32 + quad * 8];
            bf8_t kf1 = *(const bf8_t*)&Ks[16 + lr][kk * 32 + quad * 8];
            s0 = __builtin_amdgcn_mfma_f32_16x16x32_bf16(qf[kk], kf0, s0, 0, 0, 0);
            s1 = __builtin_amdgcn_mfma_f32_16x16x32_bf16(qf[kk], kf1, s1, 0, 0, 0);
        }

        const int j0 = kb + lr, j1 = kb + 16 + lr;
        float sv0[4], sv1[4];
        bool ok0[4], ok1[4];
        #pragma unroll
        for (int r = 0; r < 4; ++r) {
            int i = i_base + r;
            ok0[r] = (j0 <= i) && (i - j0 < WIN);
            ok1[r] = (j1 <= i) && (i - j1 < WIN);
            sv0[r] = ok0[r] ? s0[r] * scale : -1e30f;
            sv1[r] = ok1[r] ? s1[r] * scale : -1e30f;
        }

        float rmax[4];
        #pragma unroll
        for (int r = 0; r < 4; ++r) rmax[r] = fmaxf(sv0[r], sv1[r]);
        #pragma unroll
        for (int off = 1; off < 16; off <<= 1)
            #pragma unroll
            for (int r = 0; r < 4; ++r)
                rmax[r] = fmaxf(rmax[r], __shfl_xor(rmax[r], off));

        float alpha[4], p0[4], p1[4], rsum[4];
        #pragma unroll
        for (int r = 0; r < 4; ++r) {
            float mn = fmaxf(mrow[r], rmax[r]);
            alpha[r] = __expf(mrow[r] - mn);
            mrow[r]  = mn;
            p0[r] = ok0[r] ? __expf(sv0[r] - mn) : 0.f;
            p1[r] = ok1[r] ? __expf(sv1[r] - mn) : 0.f;
            rsum[r] = p0[r] + p1[r];
        }
        #pragma unroll
        for (int off = 1; off < 16; off <<= 1)
            #pragma unroll
            for (int r = 0; r < 4; ++r)
                rsum[r] += __shfl_xor(rsum[r], off);
        #pragma unroll
        for (int r = 0; r < 4; ++r) lrow[r] = lrow[r] * alpha[r] + rsum[r];

        #pragma unroll
        for (int dt = 0; dt < 8; ++dt)
            #pragma unroll
            for (int r = 0; r < 4; ++r)
                O[dt][r] *= alpha[r];

        #pragma unroll
        for (int r = 0; r < 4; ++r) {
            Pl[w][quad * 4 + r][lr]      = f2bf(p0[r]);
            Pl[w][quad * 4 + r][16 + lr] = f2bf(p1[r]);
        }
        bf8_t pf = *(const bf8_t*)&Pl[w][lr][quad * 8];

        #pragma unroll
        for (int dt = 0; dt < 8; ++dt) {
            bf8_t vf = *(const bf8_t*)&Vs[dt * 16 + lr][quad * 8];
            O[dt] = __builtin_amdgcn_mfma_f32_16x16x32_bf16(pf, vf, O[dt], 0, 0, 0);
        }
    }

    float invl[4];
    #pragma unroll
    for (int r = 0; r < 4; ++r) invl[r] = 1.0f / lrow[r];
    #pragma unroll
    for (int dt = 0; dt < 8; ++dt)
        #pragma unroll
        for (int r = 0; r < 4; ++r)
            Q[(size_t)(b * SEQ_T + i_base + r) * D_MODEL + h * HD + dt * 16 + lr] =
                f2bf(O[dt][r] * invl[r]);
}

// ---------------------------------------------------------------------------
extern "C" void kernel_launch(void* const* d_in, const int* in_sizes, int n_in,
                              void* d_out, int out_size, void* d_ws, size_t ws_size,
                              hipStream_t stream) {
    const float* x  = (const float*)d_in[0];
    const float* Wq = (const float*)d_in[1];
    const float* Wk = (const float*)d_in[2];
    const float* Wv = (const float*)d_in[3];
    const float* Wo = (const float*)d_in[4];
    const unsigned short* sniffp = (const unsigned short*)d_in[1];

    // ws layout (32 MiB exactly): Qb 16MB | Kb 4MB | Vtb 4MB | Wot 8MB
    unsigned short* Qb  = (unsigned short*)d_ws;
    unsigned short* Kb  = Qb + (size_t)ROWS * D_MODEL;
    unsigned short* Vtb = Kb + (size_t)ROWS * (NKVH * HD);
    unsigned short* Wot = Vtb + (size_t)(NKVH * HD) * ROWS;

    dim3 blk(256);

    if (ws_size >= (size_t)32 * 1024 * 1024) {
        // d_out as scratch until final GEMM: xb 16MB | Wqkvt 12.6MB (of 32MB)
        unsigned short* xb    = (unsigned short*)d_out;
        unsigned short* Wqkvt = xb + (size_t)ROWS * D_MODEL;   // [3072][2048]

        // --- converts (weights fused into one [3072][2048] k-major buffer) ---
        convert_x<<<dim3(ROWS * D_MODEL / (256 * 8)), blk, 0, stream>>>(x, xb);
        convert_w_t<<<dim3(D_MODEL / 32, D_MODEL / 32), blk, 0, stream>>>(
            Wq, Wqkvt, D_MODEL, D_MODEL);
        convert_w_t<<<dim3((NKVH * HD) / 32, D_MODEL / 32), blk, 0, stream>>>(
            Wk, Wqkvt + (size_t)D_MODEL * D_MODEL, D_MODEL, NKVH * HD);
        convert_w_t<<<dim3((NKVH * HD) / 32, D_MODEL / 32), blk, 0, stream>>>(
            Wv, Wqkvt + (size_t)(D_MODEL + NKVH * HD) * D_MODEL, D_MODEL, NKVH * HD);
        convert_w_t<<<dim3(D_MODEL / 32, D_MODEL / 32), blk, 0, stream>>>(
            Wo, Wot, D_MODEL, D_MODEL);

        // --- fused QKV projection + RoPE epilogue (768 blocks = 3/CU) ---
        gemm_bt128<<<dim3((D_MODEL + 2 * NKVH * HD) / 128, ROWS / 128), blk, 0, stream>>>(
            xb, Wqkvt, Qb, Kb, Vtb, ROWS, D_MODEL + 2 * NKVH * HD, D_MODEL, 3);

        // --- attention (O over Q in place) ---
        attn_mfma<<<dim3(SEQ_T / 64, NQH, BATCH), dim3(256), 0, stream>>>(Qb, Kb, Vtb);

        // --- out = O @ Wo (fp32 into d_out; scratch dead by now) ---
        gemm_bt128<<<dim3(D_MODEL / 128, ROWS / 128), blk, 0, stream>>>(
            Qb, Wot, d_out, nullptr, nullptr, ROWS, D_MODEL, D_MODEL, 1);
    } else {
        // Fallback: round-3 path (24 MB ws)
        gemm_dual<<<dim3(D_MODEL / 64, ROWS / 64), blk, 0, stream>>>(
            x, Wq, Qb, ROWS, D_MODEL, D_MODEL, sniffp, 1, 0, 0);
        gemm_dual<<<dim3((NKVH * HD) / 64, ROWS / 64), blk, 0, stream>>>(
            x, Wk, Kb, ROWS, NKVH * HD, D_MODEL, sniffp, 1, 0, 0);
        gemm_dual<<<dim3((NKVH * HD) / 64, ROWS / 64), blk, 0, stream>>>(
            x, Wv, Vtb, ROWS, NKVH * HD, D_MODEL, sniffp, 1, 0, 1);
        rope_kernel<<<dim3(ROWS * NQH), dim3(64), 0, stream>>>(Qb, NQH);
        rope_kernel<<<dim3(ROWS * NKVH), dim3(64), 0, stream>>>(Kb, NKVH);
        attn_mfma<<<dim3(SEQ_T / 64, NQH, BATCH), dim3(256), 0, stream>>>(Qb, Kb, Vtb);
        gemm_dual<<<dim3(D_MODEL / 64, ROWS / 64), blk, 0, stream>>>(
            Qb, Wo, d_out, ROWS, D_MODEL, D_MODEL, sniffp, 0, 1, 0);
    }
}